// Round 5
// baseline (762.530 us; speedup 1.0000x reference)
//
#include <hip/hip_runtime.h>
#include <cstdint>
#include <cstddef>

// Problem constants
#define NBATCH   8192
#define DFEAT    256
#define DCONV    128
#define NCLASS   5
#define NEDGE    500000
#define NUSERS   100000
#define BN_EPS   1e-3f
#define NBUCKET  128       // dst buckets of 64 rows each
#define BROWS    64
#define CAP      4608      // fixed bucket capacity (mean 3906, std 62 -> +11 sigma)
#define NPHB     16        // phase stride in bin key (power of 2)
#define NPHU     13        // used phases: src < 2^17, phase = src>>13 in 0..12

typedef unsigned short u16;
typedef short bf16x8_t __attribute__((ext_vector_type(8)));
typedef float f32x4_t  __attribute__((ext_vector_type(4)));

__device__ __forceinline__ u16 f2bf(float x) {
    unsigned u = __float_as_uint(x);
    u += 0x7FFF + ((u >> 16) & 1);
    return (u16)(u >> 16);
}
__device__ __forceinline__ float bf2f(u16 h) {
    return __uint_as_float(((unsigned)h) << 16);
}

// ============================================================================
// bf16 MFMA GEMM core: tile 64x64, block = 256 threads (4 waves), K-step 32.
// A row-major [M x K] (bf16, or f32 converted during staging when AF32=1),
// optionally row-gathered; BT row-major [N x K] bf16.
// LDS fragment-ordered -> all ds traffic conflict-free b128.
//   C/D: lane l, reg r -> row = (l>>4)*4 + r, col = l&15   (m89-verified)
// ============================================================================
template<int AF32>
__device__ __forceinline__ void mfma_tiles_t(
    const void* __restrict__ Av, int lda, const int* __restrict__ gather,
    const u16* __restrict__ BT, int K,
    int tileM, int tileN, u16* As, u16* Bs, f32x4_t acc[4])
{
    const int t    = threadIdx.x;
    const int rowi = t >> 2;
    const int kc   = t & 3;
    const int w    = t >> 6;
    const int lane = t & 63;

    int ar = gather ? gather[tileM + rowi] : (tileM + rowi);
    const u16*   Ap16 = (const u16*)Av   + (size_t)ar * lda + kc * 8;
    const float* Apf  = (const float*)Av + (size_t)ar * lda + kc * 8;
    const u16* Bp = BT + (size_t)(tileN + rowi) * K + kc * 8;
    u16* Aw = As + (size_t)(((rowi >> 4) * 64) + (rowi & 15) + 16 * kc) * 8;
    u16* Bw = Bs + (size_t)(((rowi >> 4) * 64) + (rowi & 15) + 16 * kc) * 8;
    const u16* Ar = As + (size_t)(w * 64 + lane) * 8;

    for (int k0 = 0; k0 < K; k0 += 32) {
        __syncthreads();
        if (AF32) {
            float4 a0 = *(const float4*)(Apf + k0);
            float4 a1 = *(const float4*)(Apf + k0 + 4);
            ushort4 p0, p1;
            p0.x = f2bf(a0.x); p0.y = f2bf(a0.y); p0.z = f2bf(a0.z); p0.w = f2bf(a0.w);
            p1.x = f2bf(a1.x); p1.y = f2bf(a1.y); p1.z = f2bf(a1.z); p1.w = f2bf(a1.w);
            *(ushort4*)Aw = p0;
            *(ushort4*)(Aw + 4) = p1;
        } else {
            *(uint4*)Aw = *(const uint4*)(Ap16 + k0);
        }
        *(uint4*)Bw = *(const uint4*)(Bp + k0);
        __syncthreads();
        bf16x8_t av = *(const bf16x8_t*)Ar;
        #pragma unroll
        for (int nb = 0; nb < 4; ++nb) {
            bf16x8_t bv = *(const bf16x8_t*)(Bs + (size_t)(nb * 64 + lane) * 8);
            acc[nb] = __builtin_amdgcn_mfma_f32_16x16x32_bf16(av, bv, acc[nb], 0, 0, 0);
        }
    }
}

__device__ __forceinline__ void epilogue(
    f32x4_t acc[4], int tileM, int tileN,
    const float* __restrict__ bias, const float* __restrict__ bn, int bn_ld,
    int relu, u16* __restrict__ out_bf, float* __restrict__ out_f32, int ldc)
{
    const int t = threadIdx.x, w = t >> 6, lane = t & 63;
    const int row0 = tileM + w * 16 + (lane >> 4) * 4;
    #pragma unroll
    for (int nb = 0; nb < 4; ++nb) {
        int col = tileN + nb * 16 + (lane & 15);
        float g = 1.f, be = 0.f, mu = 0.f, va = 1.f, bs = 0.f;
        if (bn)   { g = bn[col]; be = bn[bn_ld + col]; mu = bn[2 * bn_ld + col]; va = bn[3 * bn_ld + col]; }
        if (bias) bs = bias[col];
        #pragma unroll
        for (int r = 0; r < 4; ++r) {
            float x = acc[nb][r] + bs;
            if (bn)   x = g * (x - mu) * rsqrtf(va + BN_EPS) + be;
            if (relu) x = fmaxf(x, 0.f);
            size_t o = (size_t)(row0 + r) * ldc + col;
            if (out_bf) out_bf[o] = f2bf(x);
            else        out_f32[o] = x;
        }
    }
}

// ============================================================================
// R5 fusion: f path (ids 0..1023) + h projection (ids 1024..3583) in ONE
// launch (both independent inputs ready; cuts a launch boundary + packs
// blocks better: 3584 blocks vs 1024 then 2560).
// ============================================================================
__global__ __launch_bounds__(256) void k_fh(
    const float* __restrict__ uf, const float* __restrict__ itf,
    const int* __restrict__ uidx, const int* __restrict__ iidx,
    const u16* __restrict__ WTu, const u16* __restrict__ WTi,
    const float* __restrict__ bu, const float* __restrict__ bi,
    const float* __restrict__ bnu, const float* __restrict__ bni,
    u16* __restrict__ outu, u16* __restrict__ outi,
    const u16* __restrict__ agg, const u16* __restrict__ WucT, const u16* __restrict__ WicT,
    const float* __restrict__ bn_hu, const float* __restrict__ bn_hi,
    u16* __restrict__ h_user, u16* __restrict__ h_item)
{
    __shared__ __align__(16) u16 As[2048], Bs[2048];
    f32x4_t z4 = {0.f, 0.f, 0.f, 0.f};
    f32x4_t acc[4] = {z4, z4, z4, z4};
    int id = blockIdx.x;
    if (id < 1024) {
        int z  = id >> 9;
        int ny = (id >> 7) & 3;
        int mx = id & 127;
        const float* feat = z ? itf : uf;
        const int* idx  = z ? iidx : uidx;
        const u16* WT   = z ? WTi : WTu;
        const float* bias = z ? bi : bu;
        const float* bn   = z ? bni : bnu;
        u16* out = z ? outi : outu;
        int tileM = mx * 64, tileN = ny * 64;
        mfma_tiles_t<1>(feat, 256, idx, WT, 256, tileM, tileN, As, Bs, acc);
        epilogue(acc, tileM, tileN, bias, bn, 256, 1, out, nullptr, 256);
    } else {
        int r  = id - 1024;
        int cs = r >> 8;
        int ny = (r >> 7) & 1;
        int mx = r & 127;
        int c = cs % NCLASS, side = cs / NCLASS;
        const u16* A  = agg + (size_t)cs * NBATCH * DFEAT;
        const u16* BT = (side ? WicT : WucT) + (size_t)c * DCONV * DFEAT;
        const float* bn = (side ? bn_hi : bn_hu) + c * DCONV;
        u16* out = (side ? h_item : h_user) + c * DCONV;
        int tileM = mx * 64, tileN = ny * 64;
        mfma_tiles_t<0>(A, 256, nullptr, BT, 256, tileM, tileN, As, Bs, acc);
        epilogue(acc, tileM, tileN, nullptr, bn, NCLASS * DCONV, 1, out, nullptr, NCLASS * DCONV);
    }
}

// embedding, fused user(z=0)/item(z=1), K = 256 + 640
__global__ __launch_bounds__(256) void k_emb(
    const u16* __restrict__ fu, const u16* __restrict__ fi,
    const u16* __restrict__ hu, const u16* __restrict__ hi,
    const u16* __restrict__ W2fTu, const u16* __restrict__ W2hTu,
    const u16* __restrict__ W2fTi, const u16* __restrict__ W2hTi,
    u16* __restrict__ embu, u16* __restrict__ embi)
{
    __shared__ __align__(16) u16 As[2048], Bs[2048];
    f32x4_t z4 = {0.f, 0.f, 0.f, 0.f};
    f32x4_t acc[4] = {z4, z4, z4, z4};
    int z = blockIdx.z;
    const u16* fbf  = z ? fi : fu;
    const u16* hbf  = z ? hi : hu;
    const u16* W2fT = z ? W2fTi : W2fTu;
    const u16* W2hT = z ? W2hTi : W2hTu;
    u16* emb = z ? embi : embu;
    int tileM = blockIdx.x * 64, tileN = blockIdx.y * 64;
    mfma_tiles_t<0>(fbf, 256, nullptr, W2fT, 256, tileM, tileN, As, Bs, acc);
    mfma_tiles_t<0>(hbf, NCLASS * DCONV, nullptr, W2hT, NCLASS * DCONV, tileM, tileN, As, Bs, acc);
    epilogue(acc, tileM, tileN, nullptr, nullptr, 0, 1, emb, nullptr, 256);
}

__global__ __launch_bounds__(256) void k_dec(
    const u16* __restrict__ emb, const u16* __restrict__ WdecT,
    float* __restrict__ t0, float* __restrict__ t1)
{
    __shared__ __align__(16) u16 As[2048], Bs[2048];
    f32x4_t z4 = {0.f, 0.f, 0.f, 0.f};
    f32x4_t acc[4] = {z4, z4, z4, z4};
    int zi = blockIdx.z;
    const u16* BT = WdecT + (size_t)zi * 256 * 256;
    float* out = zi ? t1 : t0;
    int tileM = blockIdx.x * 64, tileN = blockIdx.y * 64;
    mfma_tiles_t<0>(emb, 256, nullptr, BT, 256, tileM, tileN, As, Bs, acc);
    epilogue(acc, tileM, tileN, nullptr, nullptr, 0, 0, nullptr, out, 256);
}

#define OFF_WFU   0
#define OFF_WFI   65536
#define OFF_WUC   131072
#define OFF_WIC   294912
#define OFF_W2FU  458752
#define OFF_W2HU  524288
#define OFF_W2FI  688128
#define OFF_W2HI  753664
#define OFF_WDEC  917504

// ============================================================================
// R5 fused prep: ONE launch for partition (ids 0..1279) + cvt_feat
// (1280..5375) + cvt_wt transpose (5376..6815). All three are independent;
// fusing removes two serialized launch boundaries and packs the device.
// ============================================================================
__global__ __launch_bounds__(256) void prep_all(
    const int* __restrict__ u_src, const int* __restrict__ u_dst, const float* __restrict__ u_w,
    const int* __restrict__ i_src, const int* __restrict__ i_dst, const float* __restrict__ i_w,
    int* __restrict__ bcur, uint2* __restrict__ part,
    const float* __restrict__ uf, const float* __restrict__ itf,
    u16* __restrict__ ubf, u16* __restrict__ ibf,
    const float* __restrict__ Wfu, const float* __restrict__ Wfi,
    const float* __restrict__ Wuc, const float* __restrict__ Wic,
    const float* __restrict__ W2fu, const float* __restrict__ W2hu,
    const float* __restrict__ W2fi, const float* __restrict__ W2hi,
    const float* __restrict__ Wdec, u16* __restrict__ wT)
{
    __shared__ union {
        struct { int hist[NBUCKET]; int cur[NBUCKET]; } p;
        float tile[32][33];
    } sm;
    int id = blockIdx.x;
    if (id < 1280) {
        // ---- partition path (128 chunks x 10 class-sides) ------------------
        int cs = id / 128;
        int bx = id - cs * 128;
        const int* srcp; const int* dstp; const float* wp;
        if (cs < NCLASS) {
            srcp = u_src + (size_t)cs * NEDGE;
            dstp = u_dst + (size_t)cs * NEDGE;
            wp   = u_w   + (size_t)cs * NEDGE;
        } else {
            int c = cs - NCLASS;
            srcp = i_src + (size_t)c * NEDGE;
            dstp = i_dst + (size_t)c * NEDGE;
            wp   = i_w   + (size_t)c * NEDGE;
        }
        int lo_e = (int)(((long long)bx * NEDGE) >> 7);
        int hi_e = (int)(((long long)(bx + 1) * NEDGE) >> 7);

        for (int i = threadIdx.x; i < NBUCKET; i += 256) sm.p.hist[i] = 0;
        __syncthreads();
        for (int e = lo_e + threadIdx.x; e < hi_e; e += 256)
            atomicAdd(&sm.p.hist[dstp[e] >> 6], 1);          // native LDS int atomic
        __syncthreads();
        for (int i = threadIdx.x; i < NBUCKET; i += 256)
            sm.p.cur[i] = atomicAdd(&bcur[cs * NBUCKET + i], sm.p.hist[i]);
        __syncthreads();
        uint2* out = part + (size_t)cs * NBUCKET * CAP;
        for (int e = lo_e + threadIdx.x; e < hi_e; e += 256) {
            int dst = dstp[e];
            int bkt = dst >> 6;
            int pos = atomicAdd(&sm.p.cur[bkt], 1);          // native LDS int atomic
            if (pos < bkt * CAP + CAP)                       // overflow guard
                out[pos] = make_uint2((unsigned)srcp[e] | ((unsigned)(dst & 63) << 24),
                                      __float_as_uint(wp[e]));
        }
    } else if (id < 1280 + 4096) {
        // ---- cvt_feat path -------------------------------------------------
        int bx = id - 1280;
        const size_t n4 = (size_t)NUSERS * DFEAT / 4;
        for (size_t i = (size_t)bx * 256 + threadIdx.x; i < 2 * n4;
             i += (size_t)4096 * 256) {
            bool u = i < n4;
            size_t j = u ? i : i - n4;
            float4 v = u ? ((const float4*)uf)[j] : ((const float4*)itf)[j];
            ushort4 o;
            o.x = f2bf(v.x); o.y = f2bf(v.y); o.z = f2bf(v.z); o.w = f2bf(v.w);
            ((ushort4*)(u ? ubf : ibf))[j] = o;
        }
    } else {
        // ---- cvt_wt path: LDS 32x33-tile transpose (coalesced both sides) --
        int r0 = id - (1280 + 4096);
        int cse = r0 / 160;                                  // case 0..8
        int tid = r0 - cse * 160;
        const float* in; u16* out; int K, N, B;
        switch (cse) {
            case 0: in = Wfu;  out = wT + OFF_WFU;  K = 256; N = 256; B = 1; break;
            case 1: in = Wfi;  out = wT + OFF_WFI;  K = 256; N = 256; B = 1; break;
            case 2: in = Wuc;  out = wT + OFF_WUC;  K = 256; N = 128; B = 5; break;
            case 3: in = Wic;  out = wT + OFF_WIC;  K = 256; N = 128; B = 5; break;
            case 4: in = W2fu; out = wT + OFF_W2FU; K = 256; N = 256; B = 1; break;
            case 5: in = W2hu; out = wT + OFF_W2HU; K = 640; N = 256; B = 1; break;
            case 6: in = W2fi; out = wT + OFF_W2FI; K = 256; N = 256; B = 1; break;
            case 7: in = W2hi; out = wT + OFF_W2HI; K = 640; N = 256; B = 1; break;
            default: in = Wdec; out = wT + OFF_WDEC; K = 256; N = 256; B = 2; break;
        }
        int tk = K >> 5, tn = N >> 5;
        if (tid >= B * tk * tn) return;
        int b  = tid / (tk * tn);
        int r  = tid - b * tk * tn;
        int kt = r % tk, nt = r / tk;
        int k0 = kt * 32, n0 = nt * 32;
        int ty = threadIdx.x >> 5, tx = threadIdx.x & 31;
        const float* ip = in + (size_t)b * K * N;
        u16* op = out + (size_t)b * N * K;
        #pragma unroll
        for (int i = 0; i < 4; ++i) {
            int row = ty + 8 * i;
            sm.tile[row][tx] = ip[(size_t)(k0 + row) * N + (n0 + tx)];
        }
        __syncthreads();
        #pragma unroll
        for (int i = 0; i < 4; ++i) {
            int row = ty + 8 * i;                            // output row in N
            op[(size_t)(n0 + row) * K + (k0 + tx)] = f2bf(sm.tile[tx][row]);
        }
    }
}

// ============================================================================
// Bucketed graph aggregation.
// R5 change: keep the (dst-row, src-phase) sort key (16 phases, XCD parity)
// for gather ORDERING, but process each row's FULL contiguous edge range
// [bin_off[row*16], bin_off[row*16+13]) as ONE segment. R4's per-(row,phase)
// segments averaged 3.8 edges -> the unroll-8 body never ran; VALUBusy hit
// 47% on tail-loop overhead while the L2-miss path sat at 2.4 TB/s (below
// its ~3.4 ceiling). Merged rows: ~61-edge segments, 8 tails/wave vs 104.
// Phase locality survives via convoy effect (equal-length rows keep waves'
// phase sweeps near-lockstep); L3 backstops the smear.
// No float atomics (R4 lesson). No fp8 (R8 lesson: absmax 25 > 11.2).
// ============================================================================
__global__ __launch_bounds__(256) void init_bcur(int* __restrict__ bcur)
{
    int i = blockIdx.x * 256 + threadIdx.x;
    if (i < 10 * NBUCKET) bcur[i] = (i & (NBUCKET - 1)) * CAP;
}

__device__ __forceinline__ int edge_key(unsigned x) {
    // (dst-low6) * NPHB + src-phase;  src < 2^17 -> phase = src>>13 in 0..12
    return (int)((x >> 24) * NPHB) + (int)((x & 0xFFFFFFu) >> 13);
}

__global__ __launch_bounds__(512) void spmm_sorted(
    const u16* __restrict__ item_bf, const u16* __restrict__ user_bf,
    const uint2* __restrict__ part, const int* __restrict__ bcur,
    u16* __restrict__ agg)
{
    __shared__ int bin_cnt[BROWS * NPHB];            // 1024 bins
    __shared__ int bin_off[BROWS * NPHB + 1];
    __shared__ int bin_cur[BROWS * NPHB];
    __shared__ int wsum[8];
    __shared__ __align__(8) uint2 sorted[CAP];       // 36864 B: sorted edge records
    // XCD parity decode: side = id&1 -> XCD (=id%8) serves exactly one table
    int id   = blockIdx.x;
    int side = id & 1;                               // 0: cs 0..4 (item tbl), 1: cs 5..9 (user tbl)
    int k    = id >> 1;
    int c    = k >> 7;
    int b    = k & 127;
    int cs   = side * NCLASS + c;
    const u16* feat = side ? user_bf : item_bf;
    int n = bcur[cs * NBUCKET + b] - b * CAP;
    if (n > CAP) n = CAP;
    const uint2* ew = part + ((size_t)cs * NBUCKET + b) * CAP;
    int tid = threadIdx.x, wave = tid >> 6, lane = tid & 63;

    bin_cnt[tid] = 0;
    bin_cnt[tid + 512] = 0;
    __syncthreads();
    for (int e = tid; e < n; e += 512)
        atomicAdd(&bin_cnt[edge_key(ew[e].x)], 1);   // native LDS int atomic
    __syncthreads();
    // ---- block-wide scan of 1024 bins: 2 bins/thread + wave shfl scan ------
    {
        int i2 = tid * 2;
        int c0 = bin_cnt[i2], c1 = bin_cnt[i2 + 1];
        int s = c0 + c1;
        int v = s;
        #pragma unroll
        for (int o = 1; o < 64; o <<= 1) {
            int u = __shfl_up(v, o);
            if (lane >= o) v += u;
        }
        if (lane == 63) wsum[wave] = v;
        __syncthreads();
        if (tid < 8) {
            int s8 = wsum[tid];
            #pragma unroll
            for (int o = 1; o < 8; o <<= 1) {
                int u = __shfl_up(s8, o);
                if (lane >= o) s8 += u;
            }
            wsum[tid] = s8;                          // inclusive wave-sum scan
        }
        __syncthreads();
        int base = (wave ? wsum[wave - 1] : 0) + (v - s);  // exclusive prefix
        bin_off[i2] = base;
        bin_off[i2 + 1] = base + c0;
        bin_cur[i2] = base;
        bin_cur[i2 + 1] = base + c0;
        if (tid == 511) bin_off[1024] = base + s;
    }
    __syncthreads();
    for (int e = tid; e < n; e += 512) {
        uint2 p = ew[e];
        int pos = atomicAdd(&bin_cur[edge_key(p.x)], 1);
        sorted[pos] = p;                             // full record into LDS
    }
    __syncthreads();

    int rowbase = cs * NBATCH + b * BROWS;
    // per-row register accumulators (statically indexed via unrolled r0)
    float ax[8], ay[8], az[8], aw[8];
    #pragma unroll
    for (int r0 = 0; r0 < 8; ++r0) { ax[r0] = 0.f; ay[r0] = 0.f; az[r0] = 0.f; aw[r0] = 0.f; }

    // Per-row MERGED segments: phases contiguous within a row (key = row*16+ph),
    // so [bin_off[row*16], bin_off[row*16+13]) is the whole row, phase-ordered.
    #pragma unroll
    for (int r0 = 0; r0 < 8; ++r0) {
        int base = (wave * 8 + r0) * NPHB;
        int j0 = bin_off[base], j1 = bin_off[base + NPHU];
        int j = j0;
        for (; j + 7 < j1; j += 8) {
            uint2 p[8];
            #pragma unroll
            for (int q = 0; q < 8; ++q) p[q] = sorted[j + q];
            ushort4 v[8];
            #pragma unroll
            for (int q = 0; q < 8; ++q)
                v[q] = *(const ushort4*)&feat[(size_t)(p[q].x & 0xFFFFFF) * DFEAT + lane * 4];
            #pragma unroll
            for (int q = 0; q < 8; ++q) {
                float w = __uint_as_float(p[q].y);
                ax[r0] += w * bf2f(v[q].x);
                ay[r0] += w * bf2f(v[q].y);
                az[r0] += w * bf2f(v[q].z);
                aw[r0] += w * bf2f(v[q].w);
            }
        }
        for (; j + 3 < j1; j += 4) {
            uint2 p0 = sorted[j], p1 = sorted[j + 1], p2 = sorted[j + 2], p3 = sorted[j + 3];
            ushort4 v0 = *(const ushort4*)&feat[(size_t)(p0.x & 0xFFFFFF) * DFEAT + lane * 4];
            ushort4 v1 = *(const ushort4*)&feat[(size_t)(p1.x & 0xFFFFFF) * DFEAT + lane * 4];
            ushort4 v2 = *(const ushort4*)&feat[(size_t)(p2.x & 0xFFFFFF) * DFEAT + lane * 4];
            ushort4 v3 = *(const ushort4*)&feat[(size_t)(p3.x & 0xFFFFFF) * DFEAT + lane * 4];
            float w0 = __uint_as_float(p0.y), w1 = __uint_as_float(p1.y);
            float w2 = __uint_as_float(p2.y), w3 = __uint_as_float(p3.y);
            ax[r0] += w0 * bf2f(v0.x) + w1 * bf2f(v1.x) + w2 * bf2f(v2.x) + w3 * bf2f(v3.x);
            ay[r0] += w0 * bf2f(v0.y) + w1 * bf2f(v1.y) + w2 * bf2f(v2.y) + w3 * bf2f(v3.y);
            az[r0] += w0 * bf2f(v0.z) + w1 * bf2f(v1.z) + w2 * bf2f(v2.z) + w3 * bf2f(v3.z);
            aw[r0] += w0 * bf2f(v0.w) + w1 * bf2f(v1.w) + w2 * bf2f(v2.w) + w3 * bf2f(v3.w);
        }
        for (; j < j1; ++j) {
            uint2 p0 = sorted[j];
            ushort4 v0 = *(const ushort4*)&feat[(size_t)(p0.x & 0xFFFFFF) * DFEAT + lane * 4];
            float w0 = __uint_as_float(p0.y);
            ax[r0] += w0 * bf2f(v0.x);
            ay[r0] += w0 * bf2f(v0.y);
            az[r0] += w0 * bf2f(v0.z);
            aw[r0] += w0 * bf2f(v0.w);
        }
    }

    #pragma unroll
    for (int r0 = 0; r0 < 8; ++r0) {
        ushort4 o4;
        o4.x = f2bf(ax[r0]); o4.y = f2bf(ay[r0]); o4.z = f2bf(az[r0]); o4.w = f2bf(aw[r0]);
        *(ushort4*)&agg[(size_t)(rowbase + wave * 8 + r0) * 256 + lane * 4] = o4;
    }
}

// ============================================================================
// decoder stage 2
// ============================================================================
__global__ __launch_bounds__(256) void decoder_kernel(
    const float* __restrict__ t0, const float* __restrict__ t1,
    const u16* __restrict__ item_emb, const float* __restrict__ Wcomb,
    float* __restrict__ out)
{
    int wave = threadIdx.x >> 6;
    int lane = threadIdx.x & 63;
    int b = blockIdx.x * 4 + wave;
    const u16*   ie = item_emb + (size_t)b * 256;
    const float* p0 = t0 + (size_t)b * 256;
    const float* p1 = t1 + (size_t)b * 256;
    float s0 = 0.f, s1 = 0.f;
    #pragma unroll
    for (int j = lane; j < 256; j += 64) {
        float v = bf2f(ie[j]);
        s0 += p0[j] * v;
        s1 += p1[j] * v;
    }
    #pragma unroll
    for (int o = 32; o > 0; o >>= 1) {
        s0 += __shfl_down(s0, o);
        s1 += __shfl_down(s1, o);
    }
    if (lane == 0) {
        #pragma unroll
        for (int r = 0; r < NCLASS; ++r)
            out[b * NCLASS + r] = Wcomb[r * 2 + 0] * s0 + Wcomb[r * 2 + 1] * s1;
    }
}

// ============================================================================
// launch
// ============================================================================
extern "C" void kernel_launch(void* const* d_in, const int* in_sizes, int n_in,
                              void* d_out, int out_size, void* d_ws, size_t ws_size,
                              hipStream_t stream)
{
    const float* user_feat = (const float*)d_in[0];
    const float* item_feat = (const float*)d_in[1];
    const int*   user_idx  = (const int*)  d_in[2];
    const int*   item_idx  = (const int*)  d_in[3];
    const int*   u_src     = (const int*)  d_in[4];
    const int*   u_dst     = (const int*)  d_in[5];
    const float* u_w       = (const float*)d_in[6];
    const int*   i_src     = (const int*)  d_in[7];
    const int*   i_dst     = (const int*)  d_in[8];
    const float* i_w       = (const float*)d_in[9];
    const float* W_fu      = (const float*)d_in[10];
    const float* b_fu      = (const float*)d_in[11];
    const float* W_fi      = (const float*)d_in[12];
    const float* b_fi      = (const float*)d_in[13];
    const float* W_uc      = (const float*)d_in[14];
    const float* W_ic      = (const float*)d_in[15];
    const float* bn_fu     = (const float*)d_in[16];
    const float* bn_hu     = (const float*)d_in[17];
    const float* bn_fi     = (const float*)d_in[18];
    const float* bn_hi     = (const float*)d_in[19];
    const float* W2_fu     = (const float*)d_in[20];
    const float* W2_hu     = (const float*)d_in[21];
    const float* W2_fi     = (const float*)d_in[22];
    const float* W2_hi     = (const float*)d_in[23];
    const float* Wdec      = (const float*)d_in[24];
    const float* Wcomb     = (const float*)d_in[25];
    float* out = (float*)d_out;

    // ---- workspace layout (193.7 MB; harness ws >= 200.4 MB proven R1) ----
    char* ws = (char*)d_ws;
    int*   bcur       = (int*)  (ws + 0);            // 1280 i32
    uint2* part_ew    = (uint2*)(ws + 65536);        // 10*128*4608*8 = 47.2 MB
    u16*   user_bf    = (u16*)  (ws + 47251456);     // 51.2 MB
    u16*   item_bf    = (u16*)  (ws + 98451456);     // 51.2 MB
    u16*   agg_bf     = (u16*)  (ws + 149651456);    // 41.9 MB (dead after hproj)
    u16*   wT         = (u16*)  (ws + 191594496);    // 2.1 MB -> end 193691648
    // overlays on part region (live f-gemm..emb, after spmm):
    u16*   f_user_bf  = (u16*)  (ws + 65536);        // 4.2 MB
    u16*   f_item_bf  = (u16*)  (ws + 4259840);      // 4.2 MB
    u16*   h_user_bf  = (u16*)  (ws + 8454144);      // 10.5 MB
    u16*   h_item_bf  = (u16*)  (ws + 18939904);     // 10.5 MB
    // overlays on agg region (live emb..decoder, after hproj):
    float* t0         = (float*)(ws + 149651456);    // 8.4 MB
    float* t1         = (float*)(ws + 158040064);    // 8.4 MB
    u16*   user_emb   = (u16*)  (ws + 166428672);    // 4.2 MB
    u16*   item_emb   = (u16*)  (ws + 170622976);    // 4.2 MB

    // ---- 1. init + fused prep (partition || cvt_feat || cvt_wt) ------------
    init_bcur<<<5, 256, 0, stream>>>(bcur);
    prep_all<<<6816, 256, 0, stream>>>(
        u_src, u_dst, u_w, i_src, i_dst, i_w, bcur, part_ew,
        user_feat, item_feat, user_bf, item_bf,
        W_fu, W_fi, W_uc, W_ic, W2_fu, W2_hu, W2_fi, W2_hi, Wdec, wT);

    // ---- 2. SpMM: XCD-parity + phase-sorted, row-merged gather -------------
    spmm_sorted<<<dim3(2 * NCLASS * NBUCKET), 512, 0, stream>>>(
        item_bf, user_bf, part_ew, bcur, agg_bf);

    // ---- 3. fused f path + h projection ------------------------------------
    k_fh<<<3584, 256, 0, stream>>>(
        user_feat, item_feat, user_idx, item_idx, wT + OFF_WFU, wT + OFF_WFI,
        b_fu, b_fi, bn_fu, bn_fi, f_user_bf, f_item_bf,
        agg_bf, wT + OFF_WUC, wT + OFF_WIC, bn_hu, bn_hi, h_user_bf, h_item_bf);

    // ---- 4. embeddings (fused user/item; agg region now dead) --------------
    k_emb<<<dim3(128, 4, 2), 256, 0, stream>>>(
        f_user_bf, f_item_bf, h_user_bf, h_item_bf,
        wT + OFF_W2FU, wT + OFF_W2HU, wT + OFF_W2FI, wT + OFF_W2HI,
        user_emb, item_emb);

    // ---- 5. decoder ---------------------------------------------------------
    k_dec<<<dim3(128, 4, 2), 256, 0, stream>>>(user_emb, wT + OFF_WDEC, t0, t1);
    decoder_kernel<<<NBATCH / 4, 256, 0, stream>>>(t0, t1, item_emb, Wcomb, out);
}

// Round 6
// 696.192 us; speedup vs baseline: 1.0953x; 1.0953x over previous
//
#include <hip/hip_runtime.h>
#include <cstdint>
#include <cstddef>

// Problem constants
#define NBATCH   8192
#define DFEAT    256
#define DCONV    128
#define NCLASS   5
#define NEDGE    500000
#define NUSERS   100000
#define BN_EPS   1e-3f
#define NBUCKET  128       // dst buckets of 64 rows each
#define BROWS    64
#define CAP      4608      // fixed bucket capacity (mean 3906, std 62 -> +11 sigma)
#define NPHB     16        // phase stride in bin key (power of 2)
#define NPHU     13        // used phases: src < 2^17, phase = src>>13 in 0..12

typedef unsigned short u16;
typedef short bf16x8_t __attribute__((ext_vector_type(8)));
typedef float f32x4_t  __attribute__((ext_vector_type(4)));

__device__ __forceinline__ u16 f2bf(float x) {
    unsigned u = __float_as_uint(x);
    u += 0x7FFF + ((u >> 16) & 1);
    return (u16)(u >> 16);
}
__device__ __forceinline__ float bf2f(u16 h) {
    return __uint_as_float(((unsigned)h) << 16);
}

// ============================================================================
// bf16 MFMA GEMM core: tile 64x64, block = 256 threads (4 waves), K-step 32.
// A row-major [M x K] (bf16, or f32 converted during staging when AF32=1),
// optionally row-gathered; BT row-major [N x K] bf16.
// LDS fragment-ordered -> all ds traffic conflict-free b128.
//   C/D: lane l, reg r -> row = (l>>4)*4 + r, col = l&15   (m89-verified)
// ============================================================================
template<int AF32>
__device__ __forceinline__ void mfma_tiles_t(
    const void* __restrict__ Av, int lda, const int* __restrict__ gather,
    const u16* __restrict__ BT, int K,
    int tileM, int tileN, u16* As, u16* Bs, f32x4_t acc[4])
{
    const int t    = threadIdx.x;
    const int rowi = t >> 2;
    const int kc   = t & 3;
    const int w    = t >> 6;
    const int lane = t & 63;

    int ar = gather ? gather[tileM + rowi] : (tileM + rowi);
    const u16*   Ap16 = (const u16*)Av   + (size_t)ar * lda + kc * 8;
    const float* Apf  = (const float*)Av + (size_t)ar * lda + kc * 8;
    const u16* Bp = BT + (size_t)(tileN + rowi) * K + kc * 8;
    u16* Aw = As + (size_t)(((rowi >> 4) * 64) + (rowi & 15) + 16 * kc) * 8;
    u16* Bw = Bs + (size_t)(((rowi >> 4) * 64) + (rowi & 15) + 16 * kc) * 8;
    const u16* Ar = As + (size_t)(w * 64 + lane) * 8;

    for (int k0 = 0; k0 < K; k0 += 32) {
        __syncthreads();
        if (AF32) {
            float4 a0 = *(const float4*)(Apf + k0);
            float4 a1 = *(const float4*)(Apf + k0 + 4);
            ushort4 p0, p1;
            p0.x = f2bf(a0.x); p0.y = f2bf(a0.y); p0.z = f2bf(a0.z); p0.w = f2bf(a0.w);
            p1.x = f2bf(a1.x); p1.y = f2bf(a1.y); p1.z = f2bf(a1.z); p1.w = f2bf(a1.w);
            *(ushort4*)Aw = p0;
            *(ushort4*)(Aw + 4) = p1;
        } else {
            *(uint4*)Aw = *(const uint4*)(Ap16 + k0);
        }
        *(uint4*)Bw = *(const uint4*)(Bp + k0);
        __syncthreads();
        bf16x8_t av = *(const bf16x8_t*)Ar;
        #pragma unroll
        for (int nb = 0; nb < 4; ++nb) {
            bf16x8_t bv = *(const bf16x8_t*)(Bs + (size_t)(nb * 64 + lane) * 8);
            acc[nb] = __builtin_amdgcn_mfma_f32_16x16x32_bf16(av, bv, acc[nb], 0, 0, 0);
        }
    }
}

__device__ __forceinline__ void epilogue(
    f32x4_t acc[4], int tileM, int tileN,
    const float* __restrict__ bias, const float* __restrict__ bn, int bn_ld,
    int relu, u16* __restrict__ out_bf, float* __restrict__ out_f32, int ldc)
{
    const int t = threadIdx.x, w = t >> 6, lane = t & 63;
    const int row0 = tileM + w * 16 + (lane >> 4) * 4;
    #pragma unroll
    for (int nb = 0; nb < 4; ++nb) {
        int col = tileN + nb * 16 + (lane & 15);
        float g = 1.f, be = 0.f, mu = 0.f, va = 1.f, bs = 0.f;
        if (bn)   { g = bn[col]; be = bn[bn_ld + col]; mu = bn[2 * bn_ld + col]; va = bn[3 * bn_ld + col]; }
        if (bias) bs = bias[col];
        #pragma unroll
        for (int r = 0; r < 4; ++r) {
            float x = acc[nb][r] + bs;
            if (bn)   x = g * (x - mu) * rsqrtf(va + BN_EPS) + be;
            if (relu) x = fmaxf(x, 0.f);
            size_t o = (size_t)(row0 + r) * ldc + col;
            if (out_bf) out_bf[o] = f2bf(x);
            else        out_f32[o] = x;
        }
    }
}

// ============================================================================
// Fused f path (ids 0..1023) + h projection (ids 1024..3583): one launch.
// ============================================================================
__global__ __launch_bounds__(256) void k_fh(
    const float* __restrict__ uf, const float* __restrict__ itf,
    const int* __restrict__ uidx, const int* __restrict__ iidx,
    const u16* __restrict__ WTu, const u16* __restrict__ WTi,
    const float* __restrict__ bu, const float* __restrict__ bi,
    const float* __restrict__ bnu, const float* __restrict__ bni,
    u16* __restrict__ outu, u16* __restrict__ outi,
    const u16* __restrict__ agg, const u16* __restrict__ WucT, const u16* __restrict__ WicT,
    const float* __restrict__ bn_hu, const float* __restrict__ bn_hi,
    u16* __restrict__ h_user, u16* __restrict__ h_item)
{
    __shared__ __align__(16) u16 As[2048], Bs[2048];
    f32x4_t z4 = {0.f, 0.f, 0.f, 0.f};
    f32x4_t acc[4] = {z4, z4, z4, z4};
    int id = blockIdx.x;
    if (id < 1024) {
        int z  = id >> 9;
        int ny = (id >> 7) & 3;
        int mx = id & 127;
        const float* feat = z ? itf : uf;
        const int* idx  = z ? iidx : uidx;
        const u16* WT   = z ? WTi : WTu;
        const float* bias = z ? bi : bu;
        const float* bn   = z ? bni : bnu;
        u16* out = z ? outi : outu;
        int tileM = mx * 64, tileN = ny * 64;
        mfma_tiles_t<1>(feat, 256, idx, WT, 256, tileM, tileN, As, Bs, acc);
        epilogue(acc, tileM, tileN, bias, bn, 256, 1, out, nullptr, 256);
    } else {
        int r  = id - 1024;
        int cs = r >> 8;
        int ny = (r >> 7) & 1;
        int mx = r & 127;
        int c = cs % NCLASS, side = cs / NCLASS;
        const u16* A  = agg + (size_t)cs * NBATCH * DFEAT;
        const u16* BT = (side ? WicT : WucT) + (size_t)c * DCONV * DFEAT;
        const float* bn = (side ? bn_hi : bn_hu) + c * DCONV;
        u16* out = (side ? h_item : h_user) + c * DCONV;
        int tileM = mx * 64, tileN = ny * 64;
        mfma_tiles_t<0>(A, 256, nullptr, BT, 256, tileM, tileN, As, Bs, acc);
        epilogue(acc, tileM, tileN, nullptr, bn, NCLASS * DCONV, 1, out, nullptr, NCLASS * DCONV);
    }
}

// embedding, fused user(z=0)/item(z=1), K = 256 + 640
__global__ __launch_bounds__(256) void k_emb(
    const u16* __restrict__ fu, const u16* __restrict__ fi,
    const u16* __restrict__ hu, const u16* __restrict__ hi,
    const u16* __restrict__ W2fTu, const u16* __restrict__ W2hTu,
    const u16* __restrict__ W2fTi, const u16* __restrict__ W2hTi,
    u16* __restrict__ embu, u16* __restrict__ embi)
{
    __shared__ __align__(16) u16 As[2048], Bs[2048];
    f32x4_t z4 = {0.f, 0.f, 0.f, 0.f};
    f32x4_t acc[4] = {z4, z4, z4, z4};
    int z = blockIdx.z;
    const u16* fbf  = z ? fi : fu;
    const u16* hbf  = z ? hi : hu;
    const u16* W2fT = z ? W2fTi : W2fTu;
    const u16* W2hT = z ? W2hTi : W2hTu;
    u16* emb = z ? embi : embu;
    int tileM = blockIdx.x * 64, tileN = blockIdx.y * 64;
    mfma_tiles_t<0>(fbf, 256, nullptr, W2fT, 256, tileM, tileN, As, Bs, acc);
    mfma_tiles_t<0>(hbf, NCLASS * DCONV, nullptr, W2hT, NCLASS * DCONV, tileM, tileN, As, Bs, acc);
    epilogue(acc, tileM, tileN, nullptr, nullptr, 0, 1, emb, nullptr, 256);
}

__global__ __launch_bounds__(256) void k_dec(
    const u16* __restrict__ emb, const u16* __restrict__ WdecT,
    float* __restrict__ t0, float* __restrict__ t1)
{
    __shared__ __align__(16) u16 As[2048], Bs[2048];
    f32x4_t z4 = {0.f, 0.f, 0.f, 0.f};
    f32x4_t acc[4] = {z4, z4, z4, z4};
    int zi = blockIdx.z;
    const u16* BT = WdecT + (size_t)zi * 256 * 256;
    float* out = zi ? t1 : t0;
    int tileM = blockIdx.x * 64, tileN = blockIdx.y * 64;
    mfma_tiles_t<0>(emb, 256, nullptr, BT, 256, tileM, tileN, As, Bs, acc);
    epilogue(acc, tileM, tileN, nullptr, nullptr, 0, 0, nullptr, out, 256);
}

#define OFF_WFU   0
#define OFF_WFI   65536
#define OFF_WUC   131072
#define OFF_WIC   294912
#define OFF_W2FU  458752
#define OFF_W2HU  524288
#define OFF_W2FI  688128
#define OFF_W2HI  753664
#define OFF_WDEC  917504

// ============================================================================
// Fused prep: partition (ids 0..1279) + cvt_feat (1280..5375) + cvt_wt
// transpose (5376..6815). All independent; one launch.
// ============================================================================
__global__ __launch_bounds__(256) void prep_all(
    const int* __restrict__ u_src, const int* __restrict__ u_dst, const float* __restrict__ u_w,
    const int* __restrict__ i_src, const int* __restrict__ i_dst, const float* __restrict__ i_w,
    int* __restrict__ bcur, uint2* __restrict__ part,
    const float* __restrict__ uf, const float* __restrict__ itf,
    u16* __restrict__ ubf, u16* __restrict__ ibf,
    const float* __restrict__ Wfu, const float* __restrict__ Wfi,
    const float* __restrict__ Wuc, const float* __restrict__ Wic,
    const float* __restrict__ W2fu, const float* __restrict__ W2hu,
    const float* __restrict__ W2fi, const float* __restrict__ W2hi,
    const float* __restrict__ Wdec, u16* __restrict__ wT)
{
    __shared__ union {
        struct { int hist[NBUCKET]; int cur[NBUCKET]; } p;
        float tile[32][33];
    } sm;
    int id = blockIdx.x;
    if (id < 1280) {
        // ---- partition path (128 chunks x 10 class-sides) ------------------
        int cs = id / 128;
        int bx = id - cs * 128;
        const int* srcp; const int* dstp; const float* wp;
        if (cs < NCLASS) {
            srcp = u_src + (size_t)cs * NEDGE;
            dstp = u_dst + (size_t)cs * NEDGE;
            wp   = u_w   + (size_t)cs * NEDGE;
        } else {
            int c = cs - NCLASS;
            srcp = i_src + (size_t)c * NEDGE;
            dstp = i_dst + (size_t)c * NEDGE;
            wp   = i_w   + (size_t)c * NEDGE;
        }
        int lo_e = (int)(((long long)bx * NEDGE) >> 7);
        int hi_e = (int)(((long long)(bx + 1) * NEDGE) >> 7);

        for (int i = threadIdx.x; i < NBUCKET; i += 256) sm.p.hist[i] = 0;
        __syncthreads();
        for (int e = lo_e + threadIdx.x; e < hi_e; e += 256)
            atomicAdd(&sm.p.hist[dstp[e] >> 6], 1);          // native LDS int atomic
        __syncthreads();
        for (int i = threadIdx.x; i < NBUCKET; i += 256)
            sm.p.cur[i] = atomicAdd(&bcur[cs * NBUCKET + i], sm.p.hist[i]);
        __syncthreads();
        uint2* out = part + (size_t)cs * NBUCKET * CAP;
        for (int e = lo_e + threadIdx.x; e < hi_e; e += 256) {
            int dst = dstp[e];
            int bkt = dst >> 6;
            int pos = atomicAdd(&sm.p.cur[bkt], 1);          // native LDS int atomic
            if (pos < bkt * CAP + CAP)                       // overflow guard
                out[pos] = make_uint2((unsigned)srcp[e] | ((unsigned)(dst & 63) << 24),
                                      __float_as_uint(wp[e]));
        }
    } else if (id < 1280 + 4096) {
        // ---- cvt_feat path -------------------------------------------------
        int bx = id - 1280;
        const size_t n4 = (size_t)NUSERS * DFEAT / 4;
        for (size_t i = (size_t)bx * 256 + threadIdx.x; i < 2 * n4;
             i += (size_t)4096 * 256) {
            bool u = i < n4;
            size_t j = u ? i : i - n4;
            float4 v = u ? ((const float4*)uf)[j] : ((const float4*)itf)[j];
            ushort4 o;
            o.x = f2bf(v.x); o.y = f2bf(v.y); o.z = f2bf(v.z); o.w = f2bf(v.w);
            ((ushort4*)(u ? ubf : ibf))[j] = o;
        }
    } else {
        // ---- cvt_wt path: LDS 32x33-tile transpose (coalesced both sides) --
        int r0 = id - (1280 + 4096);
        int cse = r0 / 160;                                  // case 0..8
        int tid = r0 - cse * 160;
        const float* in; u16* out; int K, N, B;
        switch (cse) {
            case 0: in = Wfu;  out = wT + OFF_WFU;  K = 256; N = 256; B = 1; break;
            case 1: in = Wfi;  out = wT + OFF_WFI;  K = 256; N = 256; B = 1; break;
            case 2: in = Wuc;  out = wT + OFF_WUC;  K = 256; N = 128; B = 5; break;
            case 3: in = Wic;  out = wT + OFF_WIC;  K = 256; N = 128; B = 5; break;
            case 4: in = W2fu; out = wT + OFF_W2FU; K = 256; N = 256; B = 1; break;
            case 5: in = W2hu; out = wT + OFF_W2HU; K = 640; N = 256; B = 1; break;
            case 6: in = W2fi; out = wT + OFF_W2FI; K = 256; N = 256; B = 1; break;
            case 7: in = W2hi; out = wT + OFF_W2HI; K = 640; N = 256; B = 1; break;
            default: in = Wdec; out = wT + OFF_WDEC; K = 256; N = 256; B = 2; break;
        }
        int tk = K >> 5, tn = N >> 5;
        if (tid >= B * tk * tn) return;
        int b  = tid / (tk * tn);
        int r  = tid - b * tk * tn;
        int kt = r % tk, nt = r / tk;
        int k0 = kt * 32, n0 = nt * 32;
        int ty = threadIdx.x >> 5, tx = threadIdx.x & 31;
        const float* ip = in + (size_t)b * K * N;
        u16* op = out + (size_t)b * N * K;
        #pragma unroll
        for (int i = 0; i < 4; ++i) {
            int row = ty + 8 * i;
            sm.tile[row][tx] = ip[(size_t)(k0 + row) * N + (n0 + tx)];
        }
        __syncthreads();
        #pragma unroll
        for (int i = 0; i < 4; ++i) {
            int row = ty + 8 * i;                            // output row in N
            op[(size_t)(n0 + row) * K + (k0 + tx)] = f2bf(sm.tile[tx][row]);
        }
    }
}

// ============================================================================
// Bucketed graph aggregation.
// R6: R4's per-(row,phase) segments (the proven locality structure: FETCH
// 0.66 GB with 16 phases + XCD parity; R5's row-merge proved locality comes
// ONLY from hard per-phase segment boundaries), but the segment body is a
// PREDICATED UNROLL-4 chunk: indices clamped to j1-1, weight zeroed when
// OOB. R4's segments avg 3.8 edges -> nearly every edge ran the serial
// 1-edge tail (full LDS->addr->load->FMA chain each); VALUBusy 47%. The
// predicated chunk does ~1 iteration of 4 INDEPENDENT loads per segment
// (clamped dups are L1 hits, w=0 FMAs harmless).
// No float atomics (R4 lesson). No fp8 (R8 lesson: absmax 25 > 11.2).
// ============================================================================
__global__ __launch_bounds__(256) void init_bcur(int* __restrict__ bcur)
{
    int i = blockIdx.x * 256 + threadIdx.x;
    if (i < 10 * NBUCKET) bcur[i] = (i & (NBUCKET - 1)) * CAP;
}

__device__ __forceinline__ int edge_key(unsigned x) {
    // (dst-low6) * NPHB + src-phase;  src < 2^17 -> phase = src>>13 in 0..12
    return (int)((x >> 24) * NPHB) + (int)((x & 0xFFFFFFu) >> 13);
}

__global__ __launch_bounds__(512) void spmm_sorted(
    const u16* __restrict__ item_bf, const u16* __restrict__ user_bf,
    const uint2* __restrict__ part, const int* __restrict__ bcur,
    u16* __restrict__ agg)
{
    __shared__ int bin_cnt[BROWS * NPHB];            // 1024 bins
    __shared__ int bin_off[BROWS * NPHB + 1];
    __shared__ int bin_cur[BROWS * NPHB];
    __shared__ int wsum[8];
    __shared__ __align__(8) uint2 sorted[CAP];       // 36864 B: sorted edge records
    // XCD parity decode: side = id&1 -> XCD (=id%8) serves exactly one table
    int id   = blockIdx.x;
    int side = id & 1;                               // 0: cs 0..4 (item tbl), 1: cs 5..9 (user tbl)
    int k    = id >> 1;
    int c    = k >> 7;
    int b    = k & 127;
    int cs   = side * NCLASS + c;
    const u16* feat = side ? user_bf : item_bf;
    int n = bcur[cs * NBUCKET + b] - b * CAP;
    if (n > CAP) n = CAP;
    const uint2* ew = part + ((size_t)cs * NBUCKET + b) * CAP;
    int tid = threadIdx.x, wave = tid >> 6, lane = tid & 63;

    bin_cnt[tid] = 0;
    bin_cnt[tid + 512] = 0;
    __syncthreads();
    for (int e = tid; e < n; e += 512)
        atomicAdd(&bin_cnt[edge_key(ew[e].x)], 1);   // native LDS int atomic
    __syncthreads();
    // ---- block-wide scan of 1024 bins: 2 bins/thread + wave shfl scan ------
    {
        int i2 = tid * 2;
        int c0 = bin_cnt[i2], c1 = bin_cnt[i2 + 1];
        int s = c0 + c1;
        int v = s;
        #pragma unroll
        for (int o = 1; o < 64; o <<= 1) {
            int u = __shfl_up(v, o);
            if (lane >= o) v += u;
        }
        if (lane == 63) wsum[wave] = v;
        __syncthreads();
        if (tid < 8) {
            int s8 = wsum[tid];
            #pragma unroll
            for (int o = 1; o < 8; o <<= 1) {
                int u = __shfl_up(s8, o);
                if (lane >= o) s8 += u;
            }
            wsum[tid] = s8;                          // inclusive wave-sum scan
        }
        __syncthreads();
        int base = (wave ? wsum[wave - 1] : 0) + (v - s);  // exclusive prefix
        bin_off[i2] = base;
        bin_off[i2 + 1] = base + c0;
        bin_cur[i2] = base;
        bin_cur[i2 + 1] = base + c0;
        if (tid == 511) bin_off[1024] = base + s;
    }
    __syncthreads();
    for (int e = tid; e < n; e += 512) {
        uint2 p = ew[e];
        int pos = atomicAdd(&bin_cur[edge_key(p.x)], 1);
        sorted[pos] = p;                             // full record into LDS
    }
    __syncthreads();

    int rowbase = cs * NBATCH + b * BROWS;
    // per-row register accumulators (statically indexed via unrolled r0)
    float ax[8], ay[8], az[8], aw[8];
    #pragma unroll
    for (int r0 = 0; r0 < 8; ++r0) { ax[r0] = 0.f; ay[r0] = 0.f; az[r0] = 0.f; aw[r0] = 0.f; }

    // PHASE-OUTER sweep over per-(row,phase) segments; predicated unroll-4.
    for (int ph = 0; ph < NPHU; ++ph) {
        #pragma unroll
        for (int r0 = 0; r0 < 8; ++r0) {
            int bi = (wave * 8 + r0) * NPHB + ph;
            int j0 = bin_off[bi], j1 = bin_off[bi + 1];
            for (int j = j0; j < j1; j += 4) {
                uint2 p[4];
                float w[4];
                #pragma unroll
                for (int q = 0; q < 4; ++q) {
                    int jj = j + q;
                    int jc = jj < j1 ? jj : j1 - 1;          // clamp (dup load, L1 hit)
                    p[q] = sorted[jc];
                    w[q] = jj < j1 ? __uint_as_float(p[q].y) : 0.f;
                }
                ushort4 v[4];
                #pragma unroll
                for (int q = 0; q < 4; ++q)
                    v[q] = *(const ushort4*)&feat[(size_t)(p[q].x & 0xFFFFFF) * DFEAT + lane * 4];
                #pragma unroll
                for (int q = 0; q < 4; ++q) {
                    ax[r0] += w[q] * bf2f(v[q].x);
                    ay[r0] += w[q] * bf2f(v[q].y);
                    az[r0] += w[q] * bf2f(v[q].z);
                    aw[r0] += w[q] * bf2f(v[q].w);
                }
            }
        }
    }

    #pragma unroll
    for (int r0 = 0; r0 < 8; ++r0) {
        ushort4 o4;
        o4.x = f2bf(ax[r0]); o4.y = f2bf(ay[r0]); o4.z = f2bf(az[r0]); o4.w = f2bf(aw[r0]);
        *(ushort4*)&agg[(size_t)(rowbase + wave * 8 + r0) * 256 + lane * 4] = o4;
    }
}

// ============================================================================
// decoder stage 2
// ============================================================================
__global__ __launch_bounds__(256) void decoder_kernel(
    const float* __restrict__ t0, const float* __restrict__ t1,
    const u16* __restrict__ item_emb, const float* __restrict__ Wcomb,
    float* __restrict__ out)
{
    int wave = threadIdx.x >> 6;
    int lane = threadIdx.x & 63;
    int b = blockIdx.x * 4 + wave;
    const u16*   ie = item_emb + (size_t)b * 256;
    const float* p0 = t0 + (size_t)b * 256;
    const float* p1 = t1 + (size_t)b * 256;
    float s0 = 0.f, s1 = 0.f;
    #pragma unroll
    for (int j = lane; j < 256; j += 64) {
        float v = bf2f(ie[j]);
        s0 += p0[j] * v;
        s1 += p1[j] * v;
    }
    #pragma unroll
    for (int o = 32; o > 0; o >>= 1) {
        s0 += __shfl_down(s0, o);
        s1 += __shfl_down(s1, o);
    }
    if (lane == 0) {
        #pragma unroll
        for (int r = 0; r < NCLASS; ++r)
            out[b * NCLASS + r] = Wcomb[r * 2 + 0] * s0 + Wcomb[r * 2 + 1] * s1;
    }
}

// ============================================================================
// launch
// ============================================================================
extern "C" void kernel_launch(void* const* d_in, const int* in_sizes, int n_in,
                              void* d_out, int out_size, void* d_ws, size_t ws_size,
                              hipStream_t stream)
{
    const float* user_feat = (const float*)d_in[0];
    const float* item_feat = (const float*)d_in[1];
    const int*   user_idx  = (const int*)  d_in[2];
    const int*   item_idx  = (const int*)  d_in[3];
    const int*   u_src     = (const int*)  d_in[4];
    const int*   u_dst     = (const int*)  d_in[5];
    const float* u_w       = (const float*)d_in[6];
    const int*   i_src     = (const int*)  d_in[7];
    const int*   i_dst     = (const int*)  d_in[8];
    const float* i_w       = (const float*)d_in[9];
    const float* W_fu      = (const float*)d_in[10];
    const float* b_fu      = (const float*)d_in[11];
    const float* W_fi      = (const float*)d_in[12];
    const float* b_fi      = (const float*)d_in[13];
    const float* W_uc      = (const float*)d_in[14];
    const float* W_ic      = (const float*)d_in[15];
    const float* bn_fu     = (const float*)d_in[16];
    const float* bn_hu     = (const float*)d_in[17];
    const float* bn_fi     = (const float*)d_in[18];
    const float* bn_hi     = (const float*)d_in[19];
    const float* W2_fu     = (const float*)d_in[20];
    const float* W2_hu     = (const float*)d_in[21];
    const float* W2_fi     = (const float*)d_in[22];
    const float* W2_hi     = (const float*)d_in[23];
    const float* Wdec      = (const float*)d_in[24];
    const float* Wcomb     = (const float*)d_in[25];
    float* out = (float*)d_out;

    // ---- workspace layout (193.7 MB; harness ws >= 200.4 MB proven R1) ----
    char* ws = (char*)d_ws;
    int*   bcur       = (int*)  (ws + 0);            // 1280 i32
    uint2* part_ew    = (uint2*)(ws + 65536);        // 10*128*4608*8 = 47.2 MB
    u16*   user_bf    = (u16*)  (ws + 47251456);     // 51.2 MB
    u16*   item_bf    = (u16*)  (ws + 98451456);     // 51.2 MB
    u16*   agg_bf     = (u16*)  (ws + 149651456);    // 41.9 MB (dead after hproj)
    u16*   wT         = (u16*)  (ws + 191594496);    // 2.1 MB -> end 193691648
    // overlays on part region (live f-gemm..emb, after spmm):
    u16*   f_user_bf  = (u16*)  (ws + 65536);        // 4.2 MB
    u16*   f_item_bf  = (u16*)  (ws + 4259840);      // 4.2 MB
    u16*   h_user_bf  = (u16*)  (ws + 8454144);      // 10.5 MB
    u16*   h_item_bf  = (u16*)  (ws + 18939904);     // 10.5 MB
    // overlays on agg region (live emb..decoder, after hproj):
    float* t0         = (float*)(ws + 149651456);    // 8.4 MB
    float* t1         = (float*)(ws + 158040064);    // 8.4 MB
    u16*   user_emb   = (u16*)  (ws + 166428672);    // 4.2 MB
    u16*   item_emb   = (u16*)  (ws + 170622976);    // 4.2 MB

    // ---- 1. init + fused prep (partition || cvt_feat || cvt_wt) ------------
    init_bcur<<<5, 256, 0, stream>>>(bcur);
    prep_all<<<6816, 256, 0, stream>>>(
        u_src, u_dst, u_w, i_src, i_dst, i_w, bcur, part_ew,
        user_feat, item_feat, user_bf, item_bf,
        W_fu, W_fi, W_uc, W_ic, W2_fu, W2_hu, W2_fi, W2_hi, Wdec, wT);

    // ---- 2. SpMM: XCD-parity + (row,phase) segments + predicated unroll-4 --
    spmm_sorted<<<dim3(2 * NCLASS * NBUCKET), 512, 0, stream>>>(
        item_bf, user_bf, part_ew, bcur, agg_bf);

    // ---- 3. fused f path + h projection ------------------------------------
    k_fh<<<3584, 256, 0, stream>>>(
        user_feat, item_feat, user_idx, item_idx, wT + OFF_WFU, wT + OFF_WFI,
        b_fu, b_fi, bn_fu, bn_fi, f_user_bf, f_item_bf,
        agg_bf, wT + OFF_WUC, wT + OFF_WIC, bn_hu, bn_hi, h_user_bf, h_item_bf);

    // ---- 4. embeddings (fused user/item; agg region now dead) --------------
    k_emb<<<dim3(128, 4, 2), 256, 0, stream>>>(
        f_user_bf, f_item_bf, h_user_bf, h_item_bf,
        wT + OFF_W2FU, wT + OFF_W2HU, wT + OFF_W2FI, wT + OFF_W2HI,
        user_emb, item_emb);

    // ---- 5. decoder ---------------------------------------------------------
    k_dec<<<dim3(128, 4, 2), 256, 0, stream>>>(user_emb, wT + OFF_WDEC, t0, t1);
    decoder_kernel<<<NBATCH / 4, 256, 0, stream>>>(t0, t1, item_emb, Wcomb, out);
}